// Round 9
// baseline (1743.117 us; speedup 1.0000x reference)
//
#include <hip/hip_runtime.h>
#include <hip/hip_bf16.h>

// LSTM: B=64, T=2048, D=128, H=128, gates 4H=512.
// Kernel 1: xg = x@Wx + bias  (exact f32 GEMM, unchanged)
// Kernel 2: recurrence via bf16 MFMA. 32 blocks x 1024 threads = 16 waves:
//   TWO independent batches per block (waves 0-7 -> batch 2blk, waves 8-15
//   -> batch 2blk+1). R6-R8 showed ~950cyc/step of irreducible serial
//   latency with zero TLP (all waves lockstep on one batch). Two interleaved
//   recurrences per CU hide each other's latency chains on the 4 SIMDs.
//   Per-wave structure identical to R8 (64 VGPR Wh frags, 4-deep xg
//   prefetch, post-MFMA xg add, 1 lgkm-only barrier/step, h ping-pong).

#define B_ 64
#define T_ 2048
#define D_ 128
#define H_ 128
#define G_ 512  // 4*H

typedef __bf16 v8bf __attribute__((ext_vector_type(8)));
typedef float f32x4 __attribute__((ext_vector_type(4)));

__device__ __forceinline__ float fast_exp2(float x) { return __builtin_amdgcn_exp2f(x); }
__device__ __forceinline__ float fast_rcp(float x)  { return __builtin_amdgcn_rcpf(x); }
__device__ __forceinline__ float sigmoid_(float x) {
    return fast_rcp(1.0f + fast_exp2(x * -1.44269504088896341f));
}
__device__ __forceinline__ float tanh_(float x) {
    // tanh(x) = 1 - 2/(1+2^(x*2*log2e)); saturates correctly at +-inf.
    return 1.0f - 2.0f * fast_rcp(1.0f + fast_exp2(x * 2.88539008177792682f));
}
__device__ __forceinline__ unsigned short f2bf(float f) {
    union { float f; unsigned u; } v; v.f = f;
    unsigned r = v.u + 0x7FFFu + ((v.u >> 16) & 1u);  // RNE
    return (unsigned short)(r >> 16);
}

// ---------------- Kernel 1: input projection GEMM (f32, exact) ----------------
__global__ void __launch_bounds__(256, 2)
xg_gemm_kernel(const float* __restrict__ x, const float* __restrict__ Wx,
               const float* __restrict__ bias, float* __restrict__ xg,
               int t0, int C) {
    __shared__ float xs[64 * 128];  // 32 KB: 64 rows of x
    const int tid = threadIdx.x;
    const int block_row = blockIdx.x * 64;   // row index in [0, B*C)
    const int b  = block_row / C;
    const int tl = block_row - b * C;

    const float* xrow = x + ((size_t)b * T_ + (size_t)(t0 + tl)) * D_;
    const float4* xv = (const float4*)xrow;
    float4* xsv = (float4*)xs;
#pragma unroll
    for (int i = 0; i < 8; ++i) xsv[tid + 256 * i] = xv[tid + 256 * i];
    __syncthreads();

    const int rg = tid >> 5;   // 0..7
    const int cg = tid & 31;   // 0..31

    float acc[8][16];
#pragma unroll
    for (int j2 = 0; j2 < 4; ++j2) {
        float4 bb = *(const float4*)&bias[j2 * 128 + cg * 4];
#pragma unroll
        for (int r = 0; r < 8; ++r) {
            acc[r][j2 * 4 + 0] = bb.x; acc[r][j2 * 4 + 1] = bb.y;
            acc[r][j2 * 4 + 2] = bb.z; acc[r][j2 * 4 + 3] = bb.w;
        }
    }

#pragma unroll 2
    for (int k = 0; k < 128; ++k) {
        float4 w0 = *(const float4*)&Wx[(size_t)k * G_ + 0 * 128 + cg * 4];
        float4 w1 = *(const float4*)&Wx[(size_t)k * G_ + 1 * 128 + cg * 4];
        float4 w2 = *(const float4*)&Wx[(size_t)k * G_ + 2 * 128 + cg * 4];
        float4 w3 = *(const float4*)&Wx[(size_t)k * G_ + 3 * 128 + cg * 4];
#pragma unroll
        for (int r = 0; r < 8; ++r) {
            float xval = xs[(rg * 8 + r) * 128 + k];
            acc[r][0]  = fmaf(xval, w0.x, acc[r][0]);
            acc[r][1]  = fmaf(xval, w0.y, acc[r][1]);
            acc[r][2]  = fmaf(xval, w0.z, acc[r][2]);
            acc[r][3]  = fmaf(xval, w0.w, acc[r][3]);
            acc[r][4]  = fmaf(xval, w1.x, acc[r][4]);
            acc[r][5]  = fmaf(xval, w1.y, acc[r][5]);
            acc[r][6]  = fmaf(xval, w1.z, acc[r][6]);
            acc[r][7]  = fmaf(xval, w1.w, acc[r][7]);
            acc[r][8]  = fmaf(xval, w2.x, acc[r][8]);
            acc[r][9]  = fmaf(xval, w2.y, acc[r][9]);
            acc[r][10] = fmaf(xval, w2.z, acc[r][10]);
            acc[r][11] = fmaf(xval, w2.w, acc[r][11]);
            acc[r][12] = fmaf(xval, w3.x, acc[r][12]);
            acc[r][13] = fmaf(xval, w3.y, acc[r][13]);
            acc[r][14] = fmaf(xval, w3.z, acc[r][14]);
            acc[r][15] = fmaf(xval, w3.w, acc[r][15]);
        }
    }

#pragma unroll
    for (int r = 0; r < 8; ++r) {
#pragma unroll
        for (int j2 = 0; j2 < 4; ++j2) {
            float4 v;
            v.x = acc[r][j2 * 4 + 0]; v.y = acc[r][j2 * 4 + 1];
            v.z = acc[r][j2 * 4 + 2]; v.w = acc[r][j2 * 4 + 3];
            *(float4*)&xg[((size_t)block_row + rg * 8 + r) * G_ + j2 * 128 + cg * 4] = v;
        }
    }
}

// ---------------- Kernel 2: recurrence via MFMA, 2 batches/block ----------------
// tid: grp = tid>>9 (batch sub-group), role wave = (tid>>6)&7, lane = tid&63,
// q = lane>>4, cl = lane&15, hu = role*16+cl. Batch = blockIdx.x*2 + grp.
// Per group-step: 16 MFMA (acc 0-init); gate = acc[0]+xg (4-deep prefetch);
// activations; c,h in-register; q==0 writes h bf16 to group's LDS ping-pong
// + hs/cs stores; shared raw s_barrier + lgkmcnt(0).

__global__ void __launch_bounds__(1024)
__attribute__((amdgpu_waves_per_eu(4, 4)))
lstm_rnn_mfma(const float* __restrict__ xg, const float* __restrict__ Wh,
              float* __restrict__ hs, float* __restrict__ cs,
              float* __restrict__ hstate, float* __restrict__ cstate,
              int t0, int C) {
    const int tid  = threadIdx.x;
    const int grp  = tid >> 9;           // 0 or 1
    const int lane = tid & 63;
    const int role = (tid >> 6) & 7;     // wave role within group
    const int q    = lane >> 4;          // k-quarter
    const int cl   = lane & 15;
    const int kb   = q * 8;
    const int hu   = role * 16 + cl;     // hidden unit owned
    const int bb   = blockIdx.x * 2 + grp;

    __shared__ __align__(16) unsigned short h_u16[2][2][H_];  // [grp][pingpong]

    // one-time: Wh B-fragments (16 frags = 64 VGPRs)
    v8bf whf[4][4];
#pragma unroll
    for (int kk = 0; kk < 4; ++kk) {
#pragma unroll
        for (int gc = 0; gc < 4; ++gc) {
            union { unsigned short s[8]; v8bf v; } uw;
#pragma unroll
            for (int j = 0; j < 8; ++j)
                uw.s[j] = f2bf(Wh[(size_t)(kk * 32 + kb + j) * G_ + gc * 128 + hu]);
            whf[kk][gc] = uw.v;
        }
    }

    float c = 0.0f;
    if (t0 > 0) c = cstate[bb * H_ + hu];
    if ((tid & 511) < H_)
        h_u16[grp][0][tid & 511] =
            f2bf((t0 > 0) ? hstate[bb * H_ + (tid & 511)] : 0.0f);
    __syncthreads();  // once per chunk

    const float* xgb = xg + (size_t)bb * C * G_;

    // 4-step-deep xg prefetch in named registers: xp{s}{gate}
#define LOADX(s, T_IDX) \
    float xp##s##0, xp##s##1, xp##s##2, xp##s##3; \
    { const float* xp_ = xgb + (size_t)(T_IDX) * G_; \
      xp##s##0 = xp_[hu];       xp##s##1 = xp_[128 + hu]; \
      xp##s##2 = xp_[256 + hu]; xp##s##3 = xp_[384 + hu]; }
    LOADX(0, 0) LOADX(1, 1) LOADX(2, 2) LOADX(3, 3)
#undef LOADX

#define RNN_STEP(PX0, PX1, PX2, PX3, TCUR, PR, PW)                             \
    {                                                                          \
        f32x4 a0 = {0.f, 0.f, 0.f, 0.f};                                       \
        f32x4 a1 = {0.f, 0.f, 0.f, 0.f};                                       \
        f32x4 a2 = {0.f, 0.f, 0.f, 0.f};                                       \
        f32x4 a3 = {0.f, 0.f, 0.f, 0.f};                                       \
        _Pragma("unroll")                                                      \
        for (int kk = 0; kk < 4; ++kk) {                                       \
            v8bf ha = *(const v8bf*)&h_u16[grp][PR][kk * 32 + kb];             \
            a0 = __builtin_amdgcn_mfma_f32_16x16x32_bf16(ha, whf[kk][0], a0, 0, 0, 0); \
            a1 = __builtin_amdgcn_mfma_f32_16x16x32_bf16(ha, whf[kk][1], a1, 0, 0, 0); \
            a2 = __builtin_amdgcn_mfma_f32_16x16x32_bf16(ha, whf[kk][2], a2, 0, 0, 0); \
            a3 = __builtin_amdgcn_mfma_f32_16x16x32_bf16(ha, whf[kk][3], a3, 0, 0, 0); \
        }                                                                      \
        float iv = sigmoid_(a0[0] + PX0);                                      \
        float fv = sigmoid_(a1[0] + PX1);                                      \
        float gv = tanh_(a2[0] + PX2);                                         \
        float ov = sigmoid_(a3[0] + PX3);                                      \
        c = fmaf(fv, c, iv * gv);                                              \
        float hnv = ov * tanh_(c);                                             \
        { int pf = ((TCUR) + 4 < C) ? ((TCUR) + 4) : (C - 1);                  \
          const float* xp_ = xgb + (size_t)pf * G_;                            \
          PX0 = xp_[hu];       PX1 = xp_[128 + hu];                            \
          PX2 = xp_[256 + hu]; PX3 = xp_[384 + hu]; }                          \
        if (q == 0) {                                                          \
            h_u16[grp][PW][hu] = f2bf(hnv);                                    \
            size_t off = ((size_t)bb * T_ + (size_t)(t0 + (TCUR))) * H_ + hu;  \
            hs[off] = hnv; cs[off] = c;                                        \
        }                                                                      \
        asm volatile("s_waitcnt lgkmcnt(0)\n\ts_barrier" ::: "memory");        \
    }

    for (int t = 0; t < C; t += 4) {  // C is a multiple of 64
        RNN_STEP(xp00, xp01, xp02, xp03, t,     0, 1)
        RNN_STEP(xp10, xp11, xp12, xp13, t + 1, 1, 0)
        RNN_STEP(xp20, xp21, xp22, xp23, t + 2, 0, 1)
        RNN_STEP(xp30, xp31, xp32, xp33, t + 3, 1, 0)
    }
#undef RNN_STEP

    if (q == 0) cstate[bb * H_ + hu] = c;
    // final h in group's buf 0 (C multiple of 4; last step wrote PW=0)
    if ((tid & 511) < H_) {
        int idx = tid & 511;
        unsigned ui = ((unsigned)h_u16[grp][0][idx]) << 16;
        float hf; __builtin_memcpy(&hf, &ui, 4);
        hstate[bb * H_ + idx] = hf;
    }
}

extern "C" void kernel_launch(void* const* d_in, const int* in_sizes, int n_in,
                              void* d_out, int out_size, void* d_ws, size_t ws_size,
                              hipStream_t stream) {
    const float* x    = (const float*)d_in[0];  // [64,2048,128]
    const float* Wx   = (const float*)d_in[1];  // [128,512]
    const float* Wh   = (const float*)d_in[2];  // [128,512]
    const float* bias = (const float*)d_in[3];  // [512]

    float* hs = (float*)d_out;                         // [64,2048,128]
    float* cs = hs + (size_t)B_ * T_ * H_;             // [64,2048,128]

    float* hstate = (float*)d_ws;                      // [64,128]
    float* cstate = hstate + B_ * H_;                  // [64,128]
    float* xg     = cstate + B_ * H_;                  // chunk scratch [B][C][512]

    const size_t state_floats = (size_t)2 * B_ * H_;
    size_t avail_bytes = (ws_size > state_floats * 4) ? (ws_size - state_floats * 4) : 0;
    const size_t bytes_per_t = (size_t)B_ * G_ * sizeof(float);

    int C = (int)(avail_bytes / bytes_per_t);
    if (C > T_) C = T_;
    C &= ~63;
    if (C < 64) C = 64;

    for (int t0 = 0; t0 < T_; t0 += C) {
        int Ci = (T_ - t0 < C) ? (T_ - t0) : C;
        dim3 ggrid((B_ * Ci) / 64);
        xg_gemm_kernel<<<ggrid, 256, 0, stream>>>(x, Wx, bias, xg, t0, Ci);
        lstm_rnn_mfma<<<B_ / 2, 1024, 0, stream>>>(xg, Wh, hs, cs, hstate, cstate, t0, Ci);
    }
}